// Round 16
// baseline (94.201 us; speedup 1.0000x reference)
//
#include <hip/hip_runtime.h>
#include <math.h>

#pragma clang fp contract(off)

#define CELLPX 32
#define LCAP 2048      // per-cell ordered list capacity (u16); overflow -> raw-order scan
#define MAXS 128       // stage-1 scan depth = one LDS batch

// rec (16 dwords): [0]=bx [1]=by [2]=cx-bx [3]=cy-by | [4]=cx [5]=cy [6]=ax-cx [7]=ay-cy
//                  [8]=ax [9]=ay [10]=bx-ax [11]=by-ay | [12]=inv(0 if invalid) [13..15]=i0,i1,i2
__global__ __launch_bounds__(256) void prep(
    const float* __restrict__ uv, const int* __restrict__ faces,
    float* __restrict__ recs, int* __restrict__ qCount, int nTri)
{
    if (blockIdx.x == 0 && threadIdx.x == 0) *qCount = 0;   // re-zeroed every replay
    const int f = blockIdx.x * 256 + threadIdx.x;
    if (f >= nTri) return;
    const int i0 = faces[3 * f], i1 = faces[3 * f + 1], i2 = faces[3 * f + 2];
    const float ax = uv[2 * i0], ay = uv[2 * i0 + 1];
    const float bx = uv[2 * i1], by = uv[2 * i1 + 1];
    const float cx = uv[2 * i2], cy = uv[2 * i2 + 1];
    const float area = (bx - ax) * (cy - ay) - (by - ay) * (cx - ax);  // exact ref op
    const bool valid = fabsf(area) > 1e-9f;
    float* r = recs + 16 * f;
    r[0] = bx; r[1] = by; r[2]  = cx - bx; r[3]  = cy - by;
    r[4] = cx; r[5] = cy; r[6]  = ax - cx; r[7]  = ay - cy;
    r[8] = ax; r[9] = ay; r[10] = bx - ax; r[11] = by - ay;
    r[12] = valid ? 1.0f / area : 0.f;
    ((int*)r)[13] = i0; ((int*)r)[14] = i1; ((int*)r)[15] = i2;
}

__device__ __forceinline__ bool edgeMayPass(
    float qx, float qy, float ex, float ey, float s,
    float rx0, float rx1, float ry0, float ry1)
{
    const float A = s * ex;
    const float B = -s * ey;
    const float fy = A * ((A >= 0.f ? ry1 : ry0) - qy);
    const float fx = B * ((B >= 0.f ? rx1 : rx0) - qx);
    return (fy + fx) >= -1e-5f;   // conservative margin >> fp eval error
}

__device__ __forceinline__ bool satKeep(
    const float4 r0, const float4 r1, const float4 r2, const float inv,
    float rx0, float rx1, float ry0, float ry1)
{
    if (inv == 0.f) return false;
    const float xmn = fminf(r2.x, fminf(r0.x, r1.x));
    const float xmx = fmaxf(r2.x, fmaxf(r0.x, r1.x));
    const float ymn = fminf(r2.y, fminf(r0.y, r1.y));
    const float ymx = fmaxf(r2.y, fmaxf(r0.y, r1.y));
    if (!((xmn <= rx1) & (xmx >= rx0) & (ymn <= ry1) & (ymx >= ry0))) return false;
    const float s = (inv >= 0.f) ? 1.f : -1.f;
    return edgeMayPass(r0.x, r0.y, r0.z, r0.w, s, rx0, rx1, ry0, ry1)
        && edgeMayPass(r1.x, r1.y, r1.z, r1.w, s, rx0, rx1, ry0, ry1)
        && edgeMayPass(r2.x, r2.y, r2.z, r2.w, s, rx0, rx1, ry0, ry1);
}

// K2 (R12-proven): one 1024-thread block per 32px cell; index-order scan ->
// globally ordered candidate list.
__global__ __launch_bounds__(1024) void bin32(
    const float* __restrict__ recs, unsigned short* __restrict__ lists,
    int* __restrict__ counts, int res, int nTri, int nCellX)
{
    __shared__ int waveCnt[16];
    const int cell = blockIdx.x;
    const int cellX = cell % nCellX, cellY = cell / nCellX;
    const float rf = (float)res;
    const float rx0 = ((float)(cellX * CELLPX) - 1.5f) / rf;
    const float rx1 = ((float)(cellX * CELLPX + CELLPX) + 1.5f) / rf;
    const float ry0 = ((float)(cellY * CELLPX) - 1.5f) / rf;
    const float ry1 = ((float)(cellY * CELLPX + CELLPX) + 1.5f) / rf;

    const int lane = threadIdx.x & 63, wv = threadIdx.x >> 6;
    unsigned short* myList = lists + (size_t)cell * LCAP;

    int cnt = 0;
    for (int base = 0; base < nTri; base += 1024) {
        const int t = base + threadIdx.x;
        bool keep = false;
        if (t < nTri) {
            const float4* R = (const float4*)(recs + 16 * t);   // coalesced 64B/lane
            const float4 r0 = R[0], r1 = R[1], r2 = R[2], r3 = R[3];
            keep = satKeep(r0, r1, r2, r3.x, rx0, rx1, ry0, ry1);
        }
        const unsigned long long m = __ballot(keep);
        if (lane == 0) waveCnt[wv] = __popcll(m);
        __syncthreads();
        int off = 0, tot = 0;
        #pragma unroll
        for (int w = 0; w < 16; ++w) {
            if (w < wv) off += waveCnt[w];
            tot += waveCnt[w];
        }
        const int pre = __popcll(m & ((1ull << lane) - 1ull));
        if (keep) {
            const int slot = cnt + off + pre;
            if (slot < LCAP) myList[slot] = (unsigned short)t;
        }
        __syncthreads();
        cnt += tot;   // > LCAP => raw-order mode (central cells: shallow hits anyway)
    }
    if (threadIdx.x == 0) counts[cell] = cnt;
}

// K3: ONE block per 32px cell, 256 threads, each owning a 2x2 pixel quad.
// One 128-candidate LDS batch per CELL (was per tile = 4x); each broadcast
// record load in registers serves 4 pixel tests (was 1). Unresolved pixels
// with deeper lists go to the queue.
__global__ __launch_bounds__(256) void bake32(
    const float* __restrict__ recs, const unsigned short* __restrict__ lists,
    const int* __restrict__ counts, const float* __restrict__ attr,
    float* __restrict__ out, unsigned* __restrict__ queue, int* __restrict__ qCount,
    int res, int nTri, int nCellX)
{
    __shared__ float4 L0[MAXS], L1[MAXS], L2[MAXS], L3[MAXS];
    __shared__ unsigned long long smask[2];

    const int cell = blockIdx.x;
    const int cellX = cell % nCellX, cellY = cell / nCellX;
    const int tx = threadIdx.x & 15, ty = threadIdx.x >> 4;
    const int px0 = cellX * CELLPX + tx * 2;
    const int py0 = cellY * CELLPX + ty * 2;
    const float rf = (float)res;
    const float pxf0 = ((float)px0 + 0.5f) / rf;         // exact reference ops
    const float pxf1 = ((float)(px0 + 1) + 0.5f) / rf;
    const float pyf0 = ((float)py0 + 0.5f) / rf;
    const float pyf1 = ((float)(py0 + 1) + 0.5f) / rf;
    const bool inb00 = (px0     < res) & (py0     < res);
    const bool inb10 = (px0 + 1 < res) & (py0     < res);
    const bool inb01 = (px0     < res) & (py0 + 1 < res);
    const bool inb11 = (px0 + 1 < res) & (py0 + 1 < res);

    const int count = counts[cell];              // uniform
    const bool useList = (count <= LCAP);
    const int total = useList ? count : nTri;
    const int n = min(MAXS, total);
    const unsigned short* myList = lists + (size_t)cell * LCAP;
    const int lane = threadIdx.x & 63, wv = threadIdx.x >> 6;

    // ---- fill ONE batch per cell + sign-of-inv mask ----
    bool sb = false;
    if (threadIdx.x < n) {
        const int t = useList ? (int)myList[threadIdx.x] : threadIdx.x;
        const float4* R = (const float4*)(recs + 16 * t);
        float4 r0 = R[0];
        const float4 r1 = R[1], r2 = R[2], r3 = R[3];
        sb = (__float_as_uint(r3.x) >> 31) != 0;
        if (r3.x == 0.f)   // invalid tri (raw mode): poison edge0 -> never passes
            r0 = make_float4(0.f, __builtin_huge_valf(), 1.f, 0.f);
        L0[threadIdx.x] = r0; L1[threadIdx.x] = r1;
        L2[threadIdx.x] = r2; L3[threadIdx.x] = r3;
    }
    const unsigned long long bal = __ballot(sb);
    if (lane == 0 && wv < 2) smask[wv] = bal;
    __syncthreads();
    const unsigned long long m0 = smask[0], m1 = smask[1];

    // pass test: b>=0  <=>  w==0 or signbit(w)==signbit(inv)
    auto passf = [&](const float4 T0, const float4 T1, const float4 T2,
                     unsigned sv, float pxv, float pyv) -> bool {
        const float w0 = T0.z * (pyv - T0.y) - T0.w * (pxv - T0.x);
        const float w1 = T1.z * (pyv - T1.y) - T1.w * (pxv - T1.x);
        const float w2 = T2.z * (pyv - T2.y) - T2.w * (pxv - T2.x);
        const bool c0 = (w0 == 0.f) | ((__float_as_uint(w0) >> 31) == sv);
        const bool c1 = (w1 == 0.f) | ((__float_as_uint(w1) >> 31) == sv);
        const bool c2 = (w2 == 0.f) | ((__float_as_uint(w2) >> 31) == sv);
        return c0 & c1 & c2;
    };

    int kw00 = -1, kw10 = -1, kw01 = -1, kw11 = -1;

    if (n > 0) {
        const int last = n - 1;
        float4 pA0, pA1, pA2, pB0, pB1, pB2, pC0, pC1, pC2, pD0, pD1, pD2;
        float4 qA0, qA1, qA2, qB0, qB1, qB2, qC0, qC1, qC2, qD0, qD1, qD2;

        #define LOADSET(V, BASE)                                                 \
            { const int _ka = min((BASE), last),     _kb = min((BASE) + 1, last),\
                        _kc = min((BASE) + 2, last), _kd = min((BASE) + 3, last);\
              V##A0 = L0[_ka]; V##A1 = L1[_ka]; V##A2 = L2[_ka];                 \
              V##B0 = L0[_kb]; V##B1 = L1[_kb]; V##B2 = L2[_kb];                 \
              V##C0 = L0[_kc]; V##C1 = L1[_kc]; V##C2 = L2[_kc];                 \
              V##D0 = L0[_kd]; V##D1 = L1[_kd]; V##D2 = L2[_kd]; }

        #define TCAND(Q0, Q1, Q2, KK)                                            \
            { const unsigned sv =                                                \
                  (unsigned)(((((KK) & 64) ? m1 : m0) >> ((KK) & 63)) & 1ull);   \
              if (kw00 < 0 && passf(Q0, Q1, Q2, sv, pxf0, pyf0)) kw00 = (KK);    \
              if (kw10 < 0 && passf(Q0, Q1, Q2, sv, pxf1, pyf0)) kw10 = (KK);    \
              if (kw01 < 0 && passf(Q0, Q1, Q2, sv, pxf0, pyf1)) kw01 = (KK);    \
              if (kw11 < 0 && passf(Q0, Q1, Q2, sv, pxf1, pyf1)) kw11 = (KK); }

        #define TESTSET(V, BASE)                                                 \
            { const int _ka = min((BASE), last),     _kb = min((BASE) + 1, last),\
                        _kc = min((BASE) + 2, last), _kd = min((BASE) + 3, last);\
              TCAND(V##A0, V##A1, V##A2, _ka)                                    \
              TCAND(V##B0, V##B1, V##B2, _kb)                                    \
              TCAND(V##C0, V##C1, V##C2, _kc)                                    \
              TCAND(V##D0, V##D1, V##D2, _kd) }

        bool live = !((kw00 >= 0 || !inb00) & (kw10 >= 0 || !inb10) &
                      (kw01 >= 0 || !inb01) & (kw11 >= 0 || !inb11));
        LOADSET(p, 0)
        for (int i = 0; i < n && live; i += 8) {
            LOADSET(q, i + 4)
            __builtin_amdgcn_sched_barrier(0);   // loads issued BEFORE p-tests
            TESTSET(p, i)
            LOADSET(p, i + 8)
            __builtin_amdgcn_sched_barrier(0);   // loads issued BEFORE q-tests
            TESTSET(q, i + 4)
            live = !((kw00 >= 0 || !inb00) & (kw10 >= 0 || !inb10) &
                     (kw01 >= 0 || !inb01) & (kw11 >= 0 || !inb11));
        }
        #undef LOADSET
        #undef TCAND
        #undef TESTSET
    }

    // ---- resolve each quad pixel ----
    auto writePix = [&](int kw, bool inb, int pxi, int pyi, float pxv, float pyv) {
        if (!inb) return;
        const int o = (pyi * res + pxi) * 3;
        if (kw >= 0) {   // exact reference barycentrics for the winner
            const float4 E0 = L0[kw], E1 = L1[kw], E2 = L2[kw], E3 = L3[kw];
            const float w0 = E0.z * (pyv - E0.y) - E0.w * (pxv - E0.x);
            const float w1 = E1.z * (pyv - E1.y) - E1.w * (pxv - E1.x);
            const float w2 = E2.z * (pyv - E2.y) - E2.w * (pxv - E2.x);
            const float iv = E3.x;
            const float g0 = w0 * iv, g1 = w1 * iv, g2 = w2 * iv;
            const int j0 = __float_as_int(E3.y), j1 = __float_as_int(E3.z), j2 = __float_as_int(E3.w);
            out[o + 0] = g0 * attr[3 * j0 + 0] + g1 * attr[3 * j1 + 0] + g2 * attr[3 * j2 + 0];
            out[o + 1] = g0 * attr[3 * j0 + 1] + g1 * attr[3 * j1 + 1] + g2 * attr[3 * j2 + 1];
            out[o + 2] = g0 * attr[3 * j0 + 2] + g1 * attr[3 * j1 + 2] + g2 * attr[3 * j2 + 2];
        } else if (total <= MAXS) {      // complete list scanned: truly empty pixel
            out[o + 0] = 0.f; out[o + 1] = 0.f; out[o + 2] = 0.f;
        }
    };
    writePix(kw00, inb00, px0,     py0,     pxf0, pyf0);
    writePix(kw10, inb10, px0 + 1, py0,     pxf1, pyf0);
    writePix(kw01, inb01, px0,     py0 + 1, pxf0, pyf1);
    writePix(kw11, inb11, px0 + 1, py0 + 1, pxf1, pyf1);

    // ---- defer unresolved pixels: wave-aggregated queue push, one round per slot ----
    // (queue ORDER is nondeterministic; per-pixel processing & output are not)
    auto deferPush = [&](int kw, bool inb, int pxi, int pyi) {
        const bool defer = inb && (kw < 0) && (total > MAXS);
        const unsigned long long dm = __ballot(defer);
        if (dm) {
            const int leader = (int)__builtin_ctzll(dm);
            int base = 0;
            if (lane == leader) base = atomicAdd(qCount, __popcll(dm));
            base = __shfl(base, leader, 64);
            if (defer) {
                const int pre = __popcll(dm & ((1ull << lane) - 1ull));
                queue[base + pre] = (unsigned)(pyi * res + pxi);
            }
        }
    };
    deferPush(kw00, inb00, px0,     py0);
    deferPush(kw10, inb10, px0 + 1, py0);
    deferPush(kw01, inb01, px0,     py0 + 1);
    deferPush(kw11, inb11, px0 + 1, py0 + 1);
}

// K4 (R12-proven): one wave per queued straggler (grid-stride). Ballot-scan the
// list tail 64 candidates/iter; lowest passing lane = reference argmax.
__global__ __launch_bounds__(256) void rescue(
    const float* __restrict__ recs, const unsigned short* __restrict__ lists,
    const int* __restrict__ counts, const float* __restrict__ attr,
    float* __restrict__ out, const unsigned* __restrict__ queue,
    const int* __restrict__ qCount, int res, int nTri, int nCellX)
{
    const int lane = threadIdx.x & 63;
    const int wid  = blockIdx.x * 4 + (threadIdx.x >> 6);
    const int nW   = gridDim.x * 4;
    const float rf = (float)res;
    const int qn = *qCount;   // uniform

    for (int k = wid; k < qn; k += nW) {
        const int pid = (int)queue[k];
        const int pyi = pid / res, pxi = pid - pyi * res;
        const float px = ((float)pxi + 0.5f) / rf;
        const float py = ((float)pyi + 0.5f) / rf;
        const int cell = (pyi / CELLPX) * nCellX + pxi / CELLPX;
        const int count = counts[cell];
        const bool useList = (count <= LCAP);
        const int total = useList ? count : nTri;
        const unsigned short* myList = lists + (size_t)cell * LCAP;

        bool found = false;
        for (int base = MAXS; base < total && !found; base += 64) {
            const int idx = base + lane;
            bool pass = false;
            float g0 = 0.f, g1 = 0.f, g2 = 0.f; int i0 = 0, i1 = 0, i2 = 0;
            if (idx < total) {
                const int t = useList ? (int)myList[idx] : idx;
                const float4* R = (const float4*)(recs + 16 * t);
                const float4 r0 = R[0], r1 = R[1], r2 = R[2], r3 = R[3];
                const float iv = r3.x;
                if (iv != 0.f) {
                    const float w0 = r0.z * (py - r0.y) - r0.w * (px - r0.x);
                    const float w1 = r1.z * (py - r1.y) - r1.w * (px - r1.x);
                    const float w2 = r2.z * (py - r2.y) - r2.w * (px - r2.x);
                    const float b0 = w0 * iv, b1 = w1 * iv, b2 = w2 * iv;
                    if ((b0 >= 0.f) & (b1 >= 0.f) & (b2 >= 0.f)) {
                        pass = true; g0 = b0; g1 = b1; g2 = b2;
                        i0 = __float_as_int(r3.y); i1 = __float_as_int(r3.z); i2 = __float_as_int(r3.w);
                    }
                }
            }
            const unsigned long long hm = __ballot(pass);
            if (hm) {
                if (lane == (int)__builtin_ctzll(hm)) {   // lowest index = ref argmax
                    const int o = pid * 3;
                    out[o + 0] = g0 * attr[3 * i0 + 0] + g1 * attr[3 * i1 + 0] + g2 * attr[3 * i2 + 0];
                    out[o + 1] = g0 * attr[3 * i0 + 1] + g1 * attr[3 * i1 + 1] + g2 * attr[3 * i2 + 1];
                    out[o + 2] = g0 * attr[3 * i0 + 2] + g1 * attr[3 * i1 + 2] + g2 * attr[3 * i2 + 2];
                }
                found = true;
            }
        }
        if (!found && lane == 0) {
            const int o = pid * 3;
            out[o + 0] = 0.f; out[o + 1] = 0.f; out[o + 2] = 0.f;
        }
    }
}

// ---- fallback (tiny workspace / huge nTri): proven-correct wave-per-pixel scan ----
__global__ __launch_bounds__(256) void bake_wave(
    const float* __restrict__ uv, const int* __restrict__ faces,
    const float* __restrict__ attr, float* __restrict__ out,
    int res, int nTri)
{
    const int lane = threadIdx.x & 63;
    const int wid  = blockIdx.x * (blockDim.x >> 6) + (threadIdx.x >> 6);
    const int npix = res * res;
    if (wid >= npix) return;
    const int pyi = wid / res, pxi = wid - pyi * res;
    const float rf = (float)res;
    const float px = ((float)pxi + 0.5f) / rf, py = ((float)pyi + 0.5f) / rf;
    for (int base = 0; base < nTri; base += 64) {
        const int t = base + lane;
        bool hit = false; float b0 = 0, b1 = 0, b2 = 0; int i0 = 0, i1 = 0, i2 = 0;
        if (t < nTri) {
            i0 = faces[3 * t]; i1 = faces[3 * t + 1]; i2 = faces[3 * t + 2];
            const float ax = uv[2 * i0], ay = uv[2 * i0 + 1];
            const float bx = uv[2 * i1], by = uv[2 * i1 + 1];
            const float cx = uv[2 * i2], cy = uv[2 * i2 + 1];
            const float area = (bx - ax) * (cy - ay) - (by - ay) * (cx - ax);
            if (fabsf(area) > 1e-9f) {
                const float inv = 1.0f / area;
                b0 = ((cx - bx) * (py - by) - (cy - by) * (px - bx)) * inv;
                b1 = ((ax - cx) * (py - cy) - (ay - cy) * (px - cx)) * inv;
                b2 = ((bx - ax) * (py - ay) - (by - ay) * (px - ax)) * inv;
                hit = (b0 >= 0.f) & (b1 >= 0.f) & (b2 >= 0.f);
            }
        }
        const unsigned long long m = __ballot(hit);
        if (m) {
            const int src = (int)__builtin_ctzll(m);
            b0 = __shfl(b0, src, 64); b1 = __shfl(b1, src, 64); b2 = __shfl(b2, src, 64);
            const int J0 = __shfl(i0, src, 64), J1 = __shfl(i1, src, 64), J2 = __shfl(i2, src, 64);
            if (lane == 0) {
                const int o = wid * 3;
                out[o + 0] = b0 * attr[3 * J0] + b1 * attr[3 * J1] + b2 * attr[3 * J2];
                out[o + 1] = b0 * attr[3 * J0 + 1] + b1 * attr[3 * J1 + 1] + b2 * attr[3 * J2 + 1];
                out[o + 2] = b0 * attr[3 * J0 + 2] + b1 * attr[3 * J1 + 2] + b2 * attr[3 * J2 + 2];
            }
            return;
        }
    }
    if (lane == 0) { const int o = wid * 3; out[o] = 0.f; out[o + 1] = 0.f; out[o + 2] = 0.f; }
}

extern "C" void kernel_launch(void* const* d_in, const int* in_sizes, int n_in,
                              void* d_out, int out_size, void* d_ws, size_t ws_size,
                              hipStream_t stream) {
    const float* attr  = (const float*)d_in[0];
    const float* uv    = (const float*)d_in[1];
    const int*   faces = (const int*)d_in[2];
    float*       out   = (float*)d_out;

    const int nTri = in_sizes[2] / 3;
    const int res  = (int)(sqrt((double)(out_size / 3)) + 0.5);
    const int npix = res * res;

    const int nCellX = (res + CELLPX - 1) / CELLPX;
    const int nCells = nCellX * nCellX;

    const size_t recsB  = (size_t)nTri * 64;
    const size_t cntB   = (size_t)nCells * sizeof(int);
    const size_t listB  = (size_t)nCells * LCAP * sizeof(unsigned short);
    const size_t qcB    = 64;
    const size_t queueB = (size_t)npix * sizeof(unsigned);
    const size_t need   = recsB + cntB + listB + qcB + queueB;   // ~2.6 MB

    if (nTri <= 65535 && ws_size >= need) {
        char* p = (char*)d_ws;
        float* recs = (float*)p;                    p += recsB;
        int* counts = (int*)p;                      p += cntB;
        unsigned short* lists = (unsigned short*)p; p += listB;
        int* qCount = (int*)p;                      p += qcB;
        unsigned* queue = (unsigned*)p;

        prep<<<(nTri + 255) / 256, 256, 0, stream>>>(uv, faces, recs, qCount, nTri);
        bin32<<<nCells, 1024, 0, stream>>>(recs, lists, counts, res, nTri, nCellX);
        bake32<<<nCells, 256, 0, stream>>>(recs, lists, counts, attr, out, queue, qCount,
                                           res, nTri, nCellX);
        rescue<<<4096, 256, 0, stream>>>(recs, lists, counts, attr, out, queue, qCount,
                                         res, nTri, nCellX);
    } else {
        bake_wave<<<(npix + 3) / 4, 256, 0, stream>>>(uv, faces, attr, out, res, nTri);
    }
}

// Round 17
// 54.361 us; speedup vs baseline: 1.7329x; 1.7329x over previous
//
#include <hip/hip_runtime.h>
#include <math.h>

#pragma clang fp contract(off)

#define TILE 16
#define CELLPX 32
#define LCAP 2048      // per-cell ordered list capacity (u16); overflow -> raw-order scan
#define MAXS 64        // stage-1 scan depth = one LDS batch (was 128; tail halved)

// rec (16 dwords): [0]=bx [1]=by [2]=cx-bx [3]=cy-by | [4]=cx [5]=cy [6]=ax-cx [7]=ay-cy
//                  [8]=ax [9]=ay [10]=bx-ax [11]=by-ay | [12]=inv(0 if invalid) [13..15]=i0,i1,i2
__global__ __launch_bounds__(256) void prep(
    const float* __restrict__ uv, const int* __restrict__ faces,
    float* __restrict__ recs, int* __restrict__ qCount, int nTri)
{
    if (blockIdx.x == 0 && threadIdx.x == 0) *qCount = 0;   // re-zeroed every replay
    const int f = blockIdx.x * 256 + threadIdx.x;
    if (f >= nTri) return;
    const int i0 = faces[3 * f], i1 = faces[3 * f + 1], i2 = faces[3 * f + 2];
    const float ax = uv[2 * i0], ay = uv[2 * i0 + 1];
    const float bx = uv[2 * i1], by = uv[2 * i1 + 1];
    const float cx = uv[2 * i2], cy = uv[2 * i2 + 1];
    const float area = (bx - ax) * (cy - ay) - (by - ay) * (cx - ax);  // exact ref op
    const bool valid = fabsf(area) > 1e-9f;
    float* r = recs + 16 * f;
    r[0] = bx; r[1] = by; r[2]  = cx - bx; r[3]  = cy - by;
    r[4] = cx; r[5] = cy; r[6]  = ax - cx; r[7]  = ay - cy;
    r[8] = ax; r[9] = ay; r[10] = bx - ax; r[11] = by - ay;
    r[12] = valid ? 1.0f / area : 0.f;
    ((int*)r)[13] = i0; ((int*)r)[14] = i1; ((int*)r)[15] = i2;
}

__device__ __forceinline__ bool edgeMayPass(
    float qx, float qy, float ex, float ey, float s,
    float rx0, float rx1, float ry0, float ry1)
{
    const float A = s * ex;
    const float B = -s * ey;
    const float fy = A * ((A >= 0.f ? ry1 : ry0) - qy);
    const float fx = B * ((B >= 0.f ? rx1 : rx0) - qx);
    return (fy + fx) >= -1e-5f;   // conservative margin >> fp eval error
}

__device__ __forceinline__ bool satKeep(
    const float4 r0, const float4 r1, const float4 r2, const float inv,
    float rx0, float rx1, float ry0, float ry1)
{
    if (inv == 0.f) return false;
    const float xmn = fminf(r2.x, fminf(r0.x, r1.x));
    const float xmx = fmaxf(r2.x, fmaxf(r0.x, r1.x));
    const float ymn = fminf(r2.y, fminf(r0.y, r1.y));
    const float ymx = fmaxf(r2.y, fmaxf(r0.y, r1.y));
    if (!((xmn <= rx1) & (xmx >= rx0) & (ymn <= ry1) & (ymx >= ry0))) return false;
    const float s = (inv >= 0.f) ? 1.f : -1.f;
    return edgeMayPass(r0.x, r0.y, r0.z, r0.w, s, rx0, rx1, ry0, ry1)
        && edgeMayPass(r1.x, r1.y, r1.z, r1.w, s, rx0, rx1, ry0, ry1)
        && edgeMayPass(r2.x, r2.y, r2.z, r2.w, s, rx0, rx1, ry0, ry1);
}

// K2: one 1024-thread block per 32px cell; index-order scan -> globally ordered list.
__global__ __launch_bounds__(1024) void bin32(
    const float* __restrict__ recs, unsigned short* __restrict__ lists,
    int* __restrict__ counts, int res, int nTri, int nCellX)
{
    __shared__ int waveCnt[16];
    const int cell = blockIdx.x;
    const int cellX = cell % nCellX, cellY = cell / nCellX;
    const float rf = (float)res;
    const float rx0 = ((float)(cellX * CELLPX) - 1.5f) / rf;
    const float rx1 = ((float)(cellX * CELLPX + CELLPX) + 1.5f) / rf;
    const float ry0 = ((float)(cellY * CELLPX) - 1.5f) / rf;
    const float ry1 = ((float)(cellY * CELLPX + CELLPX) + 1.5f) / rf;

    const int lane = threadIdx.x & 63, wv = threadIdx.x >> 6;
    unsigned short* myList = lists + (size_t)cell * LCAP;

    int cnt = 0;
    for (int base = 0; base < nTri; base += 1024) {
        const int t = base + threadIdx.x;
        bool keep = false;
        if (t < nTri) {
            const float4* R = (const float4*)(recs + 16 * t);   // coalesced 64B/lane
            const float4 r0 = R[0], r1 = R[1], r2 = R[2], r3 = R[3];
            keep = satKeep(r0, r1, r2, r3.x, rx0, rx1, ry0, ry1);
        }
        const unsigned long long m = __ballot(keep);
        if (lane == 0) waveCnt[wv] = __popcll(m);
        __syncthreads();
        int off = 0, tot = 0;
        #pragma unroll
        for (int w = 0; w < 16; ++w) {
            if (w < wv) off += waveCnt[w];
            tot += waveCnt[w];
        }
        const int pre = __popcll(m & ((1ull << lane) - 1ull));
        if (keep) {
            const int slot = cnt + off + pre;
            if (slot < LCAP) myList[slot] = (unsigned short)t;
        }
        __syncthreads();
        cnt += tot;   // > LCAP => raw-order mode (central cells: shallow hits anyway)
    }
    if (threadIdx.x == 0) counts[cell] = cnt;
}

// K3: one 16px tile per block, EXACTLY one 64-candidate LDS batch, scanned
// with a depth-1 ping-pong register pipeline. Unresolved pixels with deeper
// lists are pushed to a compact queue (wave-aggregated atomicAdd).
__global__ __launch_bounds__(256) void bake16(
    const float* __restrict__ recs, const unsigned short* __restrict__ lists,
    const int* __restrict__ counts, const float* __restrict__ attr,
    float* __restrict__ out, unsigned* __restrict__ queue, int* __restrict__ qCount,
    int res, int nTri, int nCellX)
{
    __shared__ float4 L0[MAXS], L1[MAXS], L2[MAXS], L3[MAXS];
    __shared__ unsigned long long smask[4];

    const int tx = threadIdx.x & 15, ty = threadIdx.x >> 4;
    const int pxi = blockIdx.x * TILE + tx;
    const int pyi = blockIdx.y * TILE + ty;
    const bool inb = (pxi < res) && (pyi < res);
    const float rf = (float)res;
    const float px = ((float)pxi + 0.5f) / rf;   // exact reference op
    const float py = ((float)pyi + 0.5f) / rf;

    const int cell = ((blockIdx.y * TILE) / CELLPX) * nCellX + (blockIdx.x * TILE) / CELLPX;
    const int count = counts[cell];              // uniform
    const bool useList = (count <= LCAP);
    const int total = useList ? count : nTri;
    const int n = min(MAXS, total);
    const unsigned short* myList = lists + (size_t)cell * LCAP;

    const int lane = threadIdx.x & 63, wv = threadIdx.x >> 6;

    // ---- fill one batch + sign-of-inv mask ----
    bool sb = false;
    if (threadIdx.x < n) {
        const int t = useList ? (int)myList[threadIdx.x] : threadIdx.x;
        const float4* R = (const float4*)(recs + 16 * t);
        float4 r0 = R[0];
        const float4 r1 = R[1], r2 = R[2], r3 = R[3];
        sb = (__float_as_uint(r3.x) >> 31) != 0;
        if (r3.x == 0.f)   // invalid tri (raw mode): poison edge0 -> never passes
            r0 = make_float4(0.f, __builtin_huge_valf(), 1.f, 0.f);
        L0[threadIdx.x] = r0; L1[threadIdx.x] = r1;
        L2[threadIdx.x] = r2; L3[threadIdx.x] = r3;
    }
    const unsigned long long bal = __ballot(sb);
    if (lane == 0) smask[wv] = bal;
    __syncthreads();
    const unsigned long long m0 = smask[0], m1 = smask[1];

    // pass test: b>=0  <=>  w==0 or signbit(w)==signbit(inv)
    auto passf = [&](const float4 T0, const float4 T1, const float4 T2,
                     unsigned sv) -> unsigned {
        const float w0 = T0.z * (py - T0.y) - T0.w * (px - T0.x);
        const float w1 = T1.z * (py - T1.y) - T1.w * (px - T1.x);
        const float w2 = T2.z * (py - T2.y) - T2.w * (px - T2.x);
        const bool c0 = (w0 == 0.f) | ((__float_as_uint(w0) >> 31) == sv);
        const bool c1 = (w1 == 0.f) | ((__float_as_uint(w1) >> 31) == sv);
        const bool c2 = (w2 == 0.f) | ((__float_as_uint(w2) >> 31) == sv);
        return (unsigned)(c0 & c1 & c2);
    };

    bool hit = false;
    int kWin = 0;

    if (inb && n > 0) {
        const int last = n - 1;
        float4 pA0, pA1, pA2, pB0, pB1, pB2, pC0, pC1, pC2, pD0, pD1, pD2;
        float4 qA0, qA1, qA2, qB0, qB1, qB2, qC0, qC1, qC2, qD0, qD1, qD2;

        #define LOADSET(V, BASE)                                                 \
            { const int _ka = min((BASE), last),     _kb = min((BASE) + 1, last),\
                        _kc = min((BASE) + 2, last), _kd = min((BASE) + 3, last);\
              V##A0 = L0[_ka]; V##A1 = L1[_ka]; V##A2 = L2[_ka];                 \
              V##B0 = L0[_kb]; V##B1 = L1[_kb]; V##B2 = L2[_kb];                 \
              V##C0 = L0[_kc]; V##C1 = L1[_kc]; V##C2 = L2[_kc];                 \
              V##D0 = L0[_kd]; V##D1 = L1[_kd]; V##D2 = L2[_kd]; }

        #define TESTSET(V, BASE)                                                 \
            if (!hit) {                                                          \
                const int _ka = min((BASE), last),     _kb = min((BASE) + 1, last),\
                          _kc = min((BASE) + 2, last), _kd = min((BASE) + 3, last);\
                const unsigned long long mw = ((BASE) & 64) ? m1 : m0;           \
                unsigned pm = 0u;                                                \
                pm |= passf(V##A0, V##A1, V##A2,                                 \
                            (unsigned)((mw >> (_ka & 63)) & 1ull)) << 0;         \
                pm |= passf(V##B0, V##B1, V##B2,                                 \
                            (unsigned)((mw >> (_kb & 63)) & 1ull)) << 1;         \
                pm |= passf(V##C0, V##C1, V##C2,                                 \
                            (unsigned)((mw >> (_kc & 63)) & 1ull)) << 2;         \
                pm |= passf(V##D0, V##D1, V##D2,                                 \
                            (unsigned)((mw >> (_kd & 63)) & 1ull)) << 3;         \
                if (pm) { hit = true;                                            \
                          kWin = min((BASE) + (int)__builtin_ctz(pm), last); }   \
            }

        LOADSET(p, 0)
        for (int i = 0; i < n && !hit; i += 8) {
            LOADSET(q, i + 4)
            __builtin_amdgcn_sched_barrier(0);   // loads issued BEFORE p-tests
            TESTSET(p, i)
            LOADSET(p, i + 8)
            __builtin_amdgcn_sched_barrier(0);   // loads issued BEFORE q-tests
            TESTSET(q, i + 4)
        }
        #undef LOADSET
        #undef TESTSET
    }

    if (inb && hit) {   // recompute exact reference barycentrics for the winner
        const int o = (pyi * res + pxi) * 3;
        const float4 E0 = L0[kWin], E1 = L1[kWin], E2 = L2[kWin], E3 = L3[kWin];
        const float w0 = E0.z * (py - E0.y) - E0.w * (px - E0.x);
        const float w1 = E1.z * (py - E1.y) - E1.w * (px - E1.x);
        const float w2 = E2.z * (py - E2.y) - E2.w * (px - E2.x);
        const float iv = E3.x;
        const float g0 = w0 * iv, g1 = w1 * iv, g2 = w2 * iv;
        const int j0 = __float_as_int(E3.y), j1 = __float_as_int(E3.z), j2 = __float_as_int(E3.w);
        out[o + 0] = g0 * attr[3 * j0 + 0] + g1 * attr[3 * j1 + 0] + g2 * attr[3 * j2 + 0];
        out[o + 1] = g0 * attr[3 * j0 + 1] + g1 * attr[3 * j1 + 1] + g2 * attr[3 * j2 + 1];
        out[o + 2] = g0 * attr[3 * j0 + 2] + g1 * attr[3 * j1 + 2] + g2 * attr[3 * j2 + 2];
    } else if (inb && total <= MAXS) {   // complete list scanned: truly empty pixel
        const int o = (pyi * res + pxi) * 3;
        out[o + 0] = 0.f; out[o + 1] = 0.f; out[o + 2] = 0.f;
    }

    // ---- defer unresolved pixels: wave-aggregated queue push ----
    // (queue ORDER is nondeterministic; per-pixel processing & output are not)
    const bool defer = inb && !hit && (total > MAXS);
    const unsigned long long dm = __ballot(defer);
    if (dm) {
        const int leader = (int)__builtin_ctzll(dm);
        int base = 0;
        if (lane == leader) base = atomicAdd(qCount, __popcll(dm));
        base = __shfl(base, leader, 64);
        if (defer) {
            const int pre = __popcll(dm & ((1ull << lane) - 1ull));
            queue[base + pre] = (unsigned)(pyi * res + pxi);
        }
    }
}

// K4: one wave per queued straggler (grid-stride). Ballot-scan the list
// tail 64 candidates/iter; lowest passing lane = reference argmax.
__global__ __launch_bounds__(256) void rescue(
    const float* __restrict__ recs, const unsigned short* __restrict__ lists,
    const int* __restrict__ counts, const float* __restrict__ attr,
    float* __restrict__ out, const unsigned* __restrict__ queue,
    const int* __restrict__ qCount, int res, int nTri, int nCellX)
{
    const int lane = threadIdx.x & 63;
    const int wid  = blockIdx.x * 4 + (threadIdx.x >> 6);
    const int nW   = gridDim.x * 4;
    const float rf = (float)res;
    const int qn = *qCount;   // uniform

    for (int k = wid; k < qn; k += nW) {
        const int pid = (int)queue[k];
        const int pyi = pid / res, pxi = pid - pyi * res;
        const float px = ((float)pxi + 0.5f) / rf;
        const float py = ((float)pyi + 0.5f) / rf;
        const int cell = (pyi / CELLPX) * nCellX + pxi / CELLPX;
        const int count = counts[cell];
        const bool useList = (count <= LCAP);
        const int total = useList ? count : nTri;
        const unsigned short* myList = lists + (size_t)cell * LCAP;

        bool found = false;
        for (int base = MAXS; base < total && !found; base += 64) {
            const int idx = base + lane;
            bool pass = false;
            float g0 = 0.f, g1 = 0.f, g2 = 0.f; int i0 = 0, i1 = 0, i2 = 0;
            if (idx < total) {
                const int t = useList ? (int)myList[idx] : idx;
                const float4* R = (const float4*)(recs + 16 * t);
                const float4 r0 = R[0], r1 = R[1], r2 = R[2], r3 = R[3];
                const float iv = r3.x;
                if (iv != 0.f) {
                    const float w0 = r0.z * (py - r0.y) - r0.w * (px - r0.x);
                    const float w1 = r1.z * (py - r1.y) - r1.w * (px - r1.x);
                    const float w2 = r2.z * (py - r2.y) - r2.w * (px - r2.x);
                    const float b0 = w0 * iv, b1 = w1 * iv, b2 = w2 * iv;
                    if ((b0 >= 0.f) & (b1 >= 0.f) & (b2 >= 0.f)) {
                        pass = true; g0 = b0; g1 = b1; g2 = b2;
                        i0 = __float_as_int(r3.y); i1 = __float_as_int(r3.z); i2 = __float_as_int(r3.w);
                    }
                }
            }
            const unsigned long long hm = __ballot(pass);
            if (hm) {
                if (lane == (int)__builtin_ctzll(hm)) {   // lowest index = ref argmax
                    const int o = pid * 3;
                    out[o + 0] = g0 * attr[3 * i0 + 0] + g1 * attr[3 * i1 + 0] + g2 * attr[3 * i2 + 0];
                    out[o + 1] = g0 * attr[3 * i0 + 1] + g1 * attr[3 * i1 + 1] + g2 * attr[3 * i2 + 1];
                    out[o + 2] = g0 * attr[3 * i0 + 2] + g1 * attr[3 * i1 + 2] + g2 * attr[3 * i2 + 2];
                }
                found = true;
            }
        }
        if (!found && lane == 0) {
            const int o = pid * 3;
            out[o + 0] = 0.f; out[o + 1] = 0.f; out[o + 2] = 0.f;
        }
    }
}

// ---- fallback (tiny workspace / huge nTri): proven-correct wave-per-pixel scan ----
__global__ __launch_bounds__(256) void bake_wave(
    const float* __restrict__ uv, const int* __restrict__ faces,
    const float* __restrict__ attr, float* __restrict__ out,
    int res, int nTri)
{
    const int lane = threadIdx.x & 63;
    const int wid  = blockIdx.x * (blockDim.x >> 6) + (threadIdx.x >> 6);
    const int npix = res * res;
    if (wid >= npix) return;
    const int pyi = wid / res, pxi = wid - pyi * res;
    const float rf = (float)res;
    const float px = ((float)pxi + 0.5f) / rf, py = ((float)pyi + 0.5f) / rf;
    for (int base = 0; base < nTri; base += 64) {
        const int t = base + lane;
        bool hit = false; float b0 = 0, b1 = 0, b2 = 0; int i0 = 0, i1 = 0, i2 = 0;
        if (t < nTri) {
            i0 = faces[3 * t]; i1 = faces[3 * t + 1]; i2 = faces[3 * t + 2];
            const float ax = uv[2 * i0], ay = uv[2 * i0 + 1];
            const float bx = uv[2 * i1], by = uv[2 * i1 + 1];
            const float cx = uv[2 * i2], cy = uv[2 * i2 + 1];
            const float area = (bx - ax) * (cy - ay) - (by - ay) * (cx - ax);
            if (fabsf(area) > 1e-9f) {
                const float inv = 1.0f / area;
                b0 = ((cx - bx) * (py - by) - (cy - by) * (px - bx)) * inv;
                b1 = ((ax - cx) * (py - cy) - (ay - cy) * (px - cx)) * inv;
                b2 = ((bx - ax) * (py - ay) - (by - ay) * (px - ax)) * inv;
                hit = (b0 >= 0.f) & (b1 >= 0.f) & (b2 >= 0.f);
            }
        }
        const unsigned long long m = __ballot(hit);
        if (m) {
            const int src = (int)__builtin_ctzll(m);
            b0 = __shfl(b0, src, 64); b1 = __shfl(b1, src, 64); b2 = __shfl(b2, src, 64);
            const int J0 = __shfl(i0, src, 64), J1 = __shfl(i1, src, 64), J2 = __shfl(i2, src, 64);
            if (lane == 0) {
                const int o = wid * 3;
                out[o + 0] = b0 * attr[3 * J0] + b1 * attr[3 * J1] + b2 * attr[3 * J2];
                out[o + 1] = b0 * attr[3 * J0 + 1] + b1 * attr[3 * J1 + 1] + b2 * attr[3 * J2 + 1];
                out[o + 2] = b0 * attr[3 * J0 + 2] + b1 * attr[3 * J1 + 2] + b2 * attr[3 * J2 + 2];
            }
            return;
        }
    }
    if (lane == 0) { const int o = wid * 3; out[o] = 0.f; out[o + 1] = 0.f; out[o + 2] = 0.f; }
}

extern "C" void kernel_launch(void* const* d_in, const int* in_sizes, int n_in,
                              void* d_out, int out_size, void* d_ws, size_t ws_size,
                              hipStream_t stream) {
    const float* attr  = (const float*)d_in[0];
    const float* uv    = (const float*)d_in[1];
    const int*   faces = (const int*)d_in[2];
    float*       out   = (float*)d_out;

    const int nTri = in_sizes[2] / 3;
    const int res  = (int)(sqrt((double)(out_size / 3)) + 0.5);
    const int npix = res * res;

    const int nCellX = (res + CELLPX - 1) / CELLPX;
    const int nCells = nCellX * nCellX;

    const size_t recsB  = (size_t)nTri * 64;
    const size_t cntB   = (size_t)nCells * sizeof(int);
    const size_t listB  = (size_t)nCells * LCAP * sizeof(unsigned short);
    const size_t qcB    = 64;
    const size_t queueB = (size_t)npix * sizeof(unsigned);
    const size_t need   = recsB + cntB + listB + qcB + queueB;   // ~2.6 MB

    if (nTri <= 65535 && ws_size >= need) {
        char* p = (char*)d_ws;
        float* recs = (float*)p;                    p += recsB;
        int* counts = (int*)p;                      p += cntB;
        unsigned short* lists = (unsigned short*)p; p += listB;
        int* qCount = (int*)p;                      p += qcB;
        unsigned* queue = (unsigned*)p;

        prep<<<(nTri + 255) / 256, 256, 0, stream>>>(uv, faces, recs, qCount, nTri);
        bin32<<<nCells, 1024, 0, stream>>>(recs, lists, counts, res, nTri, nCellX);
        dim3 grid((res + TILE - 1) / TILE, (res + TILE - 1) / TILE);
        bake16<<<grid, 256, 0, stream>>>(recs, lists, counts, attr, out, queue, qCount,
                                         res, nTri, nCellX);
        rescue<<<4096, 256, 0, stream>>>(recs, lists, counts, attr, out, queue, qCount,
                                         res, nTri, nCellX);
    } else {
        bake_wave<<<(npix + 3) / 4, 256, 0, stream>>>(uv, faces, attr, out, res, nTri);
    }
}

// Round 18
// 49.514 us; speedup vs baseline: 1.9025x; 1.0979x over previous
//
#include <hip/hip_runtime.h>
#include <math.h>

#pragma clang fp contract(off)

#define TILE 16
#define CELLPX 32
#define LCAP 2048      // per-cell ordered list capacity (u16); overflow -> raw-order scan
#define MAXS 64        // stage-1 scan depth = one LDS batch

__device__ __forceinline__ bool edgeMayPass(
    float qx, float qy, float ex, float ey, float s,
    float rx0, float rx1, float ry0, float ry1)
{
    const float A = s * ex;
    const float B = -s * ey;
    const float fy = A * ((A >= 0.f ? ry1 : ry0) - qy);
    const float fx = B * ((B >= 0.f ? rx1 : rx0) - qx);
    return (fy + fx) >= -1e-5f;   // conservative margin >> fp eval error
}

__device__ __forceinline__ bool satKeepRaw(
    const float4 r0, const float4 r1, const float4 r2, const float sgn,
    float rx0, float rx1, float ry0, float ry1)
{
    if (sgn == 0.f) return false;
    const float xmn = fminf(r2.x, fminf(r0.x, r1.x));
    const float xmx = fmaxf(r2.x, fmaxf(r0.x, r1.x));
    const float ymn = fminf(r2.y, fminf(r0.y, r1.y));
    const float ymx = fmaxf(r2.y, fmaxf(r0.y, r1.y));
    if (!((xmn <= rx1) & (xmx >= rx0) & (ymn <= ry1) & (ymx >= ry0))) return false;
    return edgeMayPass(r0.x, r0.y, r0.z, r0.w, sgn, rx0, rx1, ry0, ry1)
        && edgeMayPass(r1.x, r1.y, r1.z, r1.w, sgn, rx0, rx1, ry0, ry1)
        && edgeMayPass(r2.x, r2.y, r2.z, r2.w, sgn, rx0, rx1, ry0, ry1);
}

// K1: one 1024-thread block per 32px cell. SAT computed ON THE FLY from
// uv/faces (L1-resident; no recs dependency). Each block ALSO materializes
// its own 32-triangle slice of recs (distributed prep — no central straggler).
// rec (16 dwords): [0]=bx [1]=by [2]=cx-bx [3]=cy-by | [4]=cx [5]=cy [6]=ax-cx [7]=ay-cy
//                  [8]=ax [9]=ay [10]=bx-ax [11]=by-ay | [12]=inv(0 if invalid) [13..15]=i0,i1,i2
__global__ __launch_bounds__(1024) void bin32f(
    const float* __restrict__ uv, const int* __restrict__ faces,
    float* __restrict__ recs, unsigned short* __restrict__ lists,
    int* __restrict__ counts, int* __restrict__ qCount,
    int res, int nTri, int nCellX, int nCells)
{
    __shared__ int waveCnt[16];
    if (blockIdx.x == 0 && threadIdx.x == 0) *qCount = 0;   // re-zeroed every replay

    // ---- distributed recs materialization: this block's triangle slice ----
    const int segSz = (nTri + nCells - 1) / nCells;
    const int rBase = blockIdx.x * segSz;
    for (int t = rBase + threadIdx.x; t < min(nTri, rBase + segSz); t += 1024) {
        const int i0 = faces[3 * t], i1 = faces[3 * t + 1], i2 = faces[3 * t + 2];
        const float ax = uv[2 * i0], ay = uv[2 * i0 + 1];
        const float bx = uv[2 * i1], by = uv[2 * i1 + 1];
        const float cx = uv[2 * i2], cy = uv[2 * i2 + 1];
        const float area = (bx - ax) * (cy - ay) - (by - ay) * (cx - ax);  // exact ref op
        const bool valid = fabsf(area) > 1e-9f;
        float* r = recs + 16 * t;
        r[0] = bx; r[1] = by; r[2]  = cx - bx; r[3]  = cy - by;
        r[4] = cx; r[5] = cy; r[6]  = ax - cx; r[7]  = ay - cy;
        r[8] = ax; r[9] = ay; r[10] = bx - ax; r[11] = by - ay;
        r[12] = valid ? 1.0f / area : 0.f;    // IEEE div, matches reference
        ((int*)r)[13] = i0; ((int*)r)[14] = i1; ((int*)r)[15] = i2;
    }

    // ---- binning: index-order scan -> globally ordered candidate list ----
    const int cell = blockIdx.x;
    const int cellX = cell % nCellX, cellY = cell / nCellX;
    const float rf = (float)res;
    const float rx0 = ((float)(cellX * CELLPX) - 1.5f) / rf;
    const float rx1 = ((float)(cellX * CELLPX + CELLPX) + 1.5f) / rf;
    const float ry0 = ((float)(cellY * CELLPX) - 1.5f) / rf;
    const float ry1 = ((float)(cellY * CELLPX + CELLPX) + 1.5f) / rf;

    const int lane = threadIdx.x & 63, wv = threadIdx.x >> 6;
    unsigned short* myList = lists + (size_t)cell * LCAP;

    int cnt = 0;
    for (int base = 0; base < nTri; base += 1024) {
        const int t = base + threadIdx.x;
        bool keep = false;
        if (t < nTri) {
            const int i0 = faces[3 * t], i1 = faces[3 * t + 1], i2 = faces[3 * t + 2];
            const float ax = uv[2 * i0], ay = uv[2 * i0 + 1];
            const float bx = uv[2 * i1], by = uv[2 * i1 + 1];
            const float cx = uv[2 * i2], cy = uv[2 * i2 + 1];
            const float area = (bx - ax) * (cy - ay) - (by - ay) * (cx - ax);  // exact ref op
            const float sgn = (fabsf(area) > 1e-9f) ? ((area >= 0.f) ? 1.f : -1.f) : 0.f;
            const float4 r0 = make_float4(bx, by, cx - bx, cy - by);
            const float4 r1 = make_float4(cx, cy, ax - cx, ay - cy);
            const float4 r2 = make_float4(ax, ay, bx - ax, by - ay);
            keep = satKeepRaw(r0, r1, r2, sgn, rx0, rx1, ry0, ry1);
        }
        const unsigned long long m = __ballot(keep);
        if (lane == 0) waveCnt[wv] = __popcll(m);
        __syncthreads();
        int off = 0, tot = 0;
        #pragma unroll
        for (int w = 0; w < 16; ++w) {
            if (w < wv) off += waveCnt[w];
            tot += waveCnt[w];
        }
        const int pre = __popcll(m & ((1ull << lane) - 1ull));
        if (keep) {
            const int slot = cnt + off + pre;
            if (slot < LCAP) myList[slot] = (unsigned short)t;
        }
        __syncthreads();
        cnt += tot;   // > LCAP => raw-order mode (central cells: shallow hits anyway)
    }
    if (threadIdx.x == 0) counts[cell] = cnt;
}

// K2: one 16px tile per block, EXACTLY one 64-candidate LDS batch, scanned
// with a depth-1 ping-pong register pipeline. Unresolved pixels with deeper
// lists are pushed to a compact queue (wave-aggregated atomicAdd).
__global__ __launch_bounds__(256) void bake16(
    const float* __restrict__ recs, const unsigned short* __restrict__ lists,
    const int* __restrict__ counts, const float* __restrict__ attr,
    float* __restrict__ out, unsigned* __restrict__ queue, int* __restrict__ qCount,
    int res, int nTri, int nCellX)
{
    __shared__ float4 L0[MAXS], L1[MAXS], L2[MAXS], L3[MAXS];
    __shared__ unsigned long long smask[4];

    const int tx = threadIdx.x & 15, ty = threadIdx.x >> 4;
    const int pxi = blockIdx.x * TILE + tx;
    const int pyi = blockIdx.y * TILE + ty;
    const bool inb = (pxi < res) && (pyi < res);
    const float rf = (float)res;
    const float px = ((float)pxi + 0.5f) / rf;   // exact reference op
    const float py = ((float)pyi + 0.5f) / rf;

    const int cell = ((blockIdx.y * TILE) / CELLPX) * nCellX + (blockIdx.x * TILE) / CELLPX;
    const int count = counts[cell];              // uniform
    const bool useList = (count <= LCAP);
    const int total = useList ? count : nTri;
    const int n = min(MAXS, total);
    const unsigned short* myList = lists + (size_t)cell * LCAP;

    const int lane = threadIdx.x & 63, wv = threadIdx.x >> 6;

    // ---- fill one batch + sign-of-inv mask ----
    bool sb = false;
    if (threadIdx.x < n) {
        const int t = useList ? (int)myList[threadIdx.x] : threadIdx.x;
        const float4* R = (const float4*)(recs + 16 * t);
        float4 r0 = R[0];
        const float4 r1 = R[1], r2 = R[2], r3 = R[3];
        sb = (__float_as_uint(r3.x) >> 31) != 0;
        if (r3.x == 0.f)   // invalid tri (raw mode): poison edge0 -> never passes
            r0 = make_float4(0.f, __builtin_huge_valf(), 1.f, 0.f);
        L0[threadIdx.x] = r0; L1[threadIdx.x] = r1;
        L2[threadIdx.x] = r2; L3[threadIdx.x] = r3;
    }
    const unsigned long long bal = __ballot(sb);
    if (lane == 0) smask[wv] = bal;
    __syncthreads();
    const unsigned long long m0 = smask[0], m1 = smask[1];

    // pass test: b>=0  <=>  w==0 or signbit(w)==signbit(inv)
    auto passf = [&](const float4 T0, const float4 T1, const float4 T2,
                     unsigned sv) -> unsigned {
        const float w0 = T0.z * (py - T0.y) - T0.w * (px - T0.x);
        const float w1 = T1.z * (py - T1.y) - T1.w * (px - T1.x);
        const float w2 = T2.z * (py - T2.y) - T2.w * (px - T2.x);
        const bool c0 = (w0 == 0.f) | ((__float_as_uint(w0) >> 31) == sv);
        const bool c1 = (w1 == 0.f) | ((__float_as_uint(w1) >> 31) == sv);
        const bool c2 = (w2 == 0.f) | ((__float_as_uint(w2) >> 31) == sv);
        return (unsigned)(c0 & c1 & c2);
    };

    bool hit = false;
    int kWin = 0;

    if (inb && n > 0) {
        const int last = n - 1;
        float4 pA0, pA1, pA2, pB0, pB1, pB2, pC0, pC1, pC2, pD0, pD1, pD2;
        float4 qA0, qA1, qA2, qB0, qB1, qB2, qC0, qC1, qC2, qD0, qD1, qD2;

        #define LOADSET(V, BASE)                                                 \
            { const int _ka = min((BASE), last),     _kb = min((BASE) + 1, last),\
                        _kc = min((BASE) + 2, last), _kd = min((BASE) + 3, last);\
              V##A0 = L0[_ka]; V##A1 = L1[_ka]; V##A2 = L2[_ka];                 \
              V##B0 = L0[_kb]; V##B1 = L1[_kb]; V##B2 = L2[_kb];                 \
              V##C0 = L0[_kc]; V##C1 = L1[_kc]; V##C2 = L2[_kc];                 \
              V##D0 = L0[_kd]; V##D1 = L1[_kd]; V##D2 = L2[_kd]; }

        #define TESTSET(V, BASE)                                                 \
            if (!hit) {                                                          \
                const int _ka = min((BASE), last),     _kb = min((BASE) + 1, last),\
                          _kc = min((BASE) + 2, last), _kd = min((BASE) + 3, last);\
                const unsigned long long mw = ((BASE) & 64) ? m1 : m0;           \
                unsigned pm = 0u;                                                \
                pm |= passf(V##A0, V##A1, V##A2,                                 \
                            (unsigned)((mw >> (_ka & 63)) & 1ull)) << 0;         \
                pm |= passf(V##B0, V##B1, V##B2,                                 \
                            (unsigned)((mw >> (_kb & 63)) & 1ull)) << 1;         \
                pm |= passf(V##C0, V##C1, V##C2,                                 \
                            (unsigned)((mw >> (_kc & 63)) & 1ull)) << 2;         \
                pm |= passf(V##D0, V##D1, V##D2,                                 \
                            (unsigned)((mw >> (_kd & 63)) & 1ull)) << 3;         \
                if (pm) { hit = true;                                            \
                          kWin = min((BASE) + (int)__builtin_ctz(pm), last); }   \
            }

        LOADSET(p, 0)
        for (int i = 0; i < n && !hit; i += 8) {
            LOADSET(q, i + 4)
            __builtin_amdgcn_sched_barrier(0);   // loads issued BEFORE p-tests
            TESTSET(p, i)
            LOADSET(p, i + 8)
            __builtin_amdgcn_sched_barrier(0);   // loads issued BEFORE q-tests
            TESTSET(q, i + 4)
        }
        #undef LOADSET
        #undef TESTSET
    }

    if (inb && hit) {   // recompute exact reference barycentrics for the winner
        const int o = (pyi * res + pxi) * 3;
        const float4 E0 = L0[kWin], E1 = L1[kWin], E2 = L2[kWin], E3 = L3[kWin];
        const float w0 = E0.z * (py - E0.y) - E0.w * (px - E0.x);
        const float w1 = E1.z * (py - E1.y) - E1.w * (px - E1.x);
        const float w2 = E2.z * (py - E2.y) - E2.w * (px - E2.x);
        const float iv = E3.x;
        const float g0 = w0 * iv, g1 = w1 * iv, g2 = w2 * iv;
        const int j0 = __float_as_int(E3.y), j1 = __float_as_int(E3.z), j2 = __float_as_int(E3.w);
        out[o + 0] = g0 * attr[3 * j0 + 0] + g1 * attr[3 * j1 + 0] + g2 * attr[3 * j2 + 0];
        out[o + 1] = g0 * attr[3 * j0 + 1] + g1 * attr[3 * j1 + 1] + g2 * attr[3 * j2 + 1];
        out[o + 2] = g0 * attr[3 * j0 + 2] + g1 * attr[3 * j1 + 2] + g2 * attr[3 * j2 + 2];
    } else if (inb && total <= MAXS) {   // complete list scanned: truly empty pixel
        const int o = (pyi * res + pxi) * 3;
        out[o + 0] = 0.f; out[o + 1] = 0.f; out[o + 2] = 0.f;
    }

    // ---- defer unresolved pixels: wave-aggregated queue push ----
    // (queue ORDER is nondeterministic; per-pixel processing & output are not)
    const bool defer = inb && !hit && (total > MAXS);
    const unsigned long long dm = __ballot(defer);
    if (dm) {
        const int leader = (int)__builtin_ctzll(dm);
        int base = 0;
        if (lane == leader) base = atomicAdd(qCount, __popcll(dm));
        base = __shfl(base, leader, 64);
        if (defer) {
            const int pre = __popcll(dm & ((1ull << lane) - 1ull));
            queue[base + pre] = (unsigned)(pyi * res + pxi);
        }
    }
}

// K3: one wave per queued straggler (grid-stride). Ballot-scan the list
// tail 64 candidates/iter; lowest passing lane = reference argmax.
__global__ __launch_bounds__(256) void rescue(
    const float* __restrict__ recs, const unsigned short* __restrict__ lists,
    const int* __restrict__ counts, const float* __restrict__ attr,
    float* __restrict__ out, const unsigned* __restrict__ queue,
    const int* __restrict__ qCount, int res, int nTri, int nCellX)
{
    const int lane = threadIdx.x & 63;
    const int wid  = blockIdx.x * 4 + (threadIdx.x >> 6);
    const int nW   = gridDim.x * 4;
    const float rf = (float)res;
    const int qn = *qCount;   // uniform

    for (int k = wid; k < qn; k += nW) {
        const int pid = (int)queue[k];
        const int pyi = pid / res, pxi = pid - pyi * res;
        const float px = ((float)pxi + 0.5f) / rf;
        const float py = ((float)pyi + 0.5f) / rf;
        const int cell = (pyi / CELLPX) * nCellX + pxi / CELLPX;
        const int count = counts[cell];
        const bool useList = (count <= LCAP);
        const int total = useList ? count : nTri;
        const unsigned short* myList = lists + (size_t)cell * LCAP;

        bool found = false;
        for (int base = MAXS; base < total && !found; base += 64) {
            const int idx = base + lane;
            bool pass = false;
            float g0 = 0.f, g1 = 0.f, g2 = 0.f; int i0 = 0, i1 = 0, i2 = 0;
            if (idx < total) {
                const int t = useList ? (int)myList[idx] : idx;
                const float4* R = (const float4*)(recs + 16 * t);
                const float4 r0 = R[0], r1 = R[1], r2 = R[2], r3 = R[3];
                const float iv = r3.x;
                if (iv != 0.f) {
                    const float w0 = r0.z * (py - r0.y) - r0.w * (px - r0.x);
                    const float w1 = r1.z * (py - r1.y) - r1.w * (px - r1.x);
                    const float w2 = r2.z * (py - r2.y) - r2.w * (px - r2.x);
                    const float b0 = w0 * iv, b1 = w1 * iv, b2 = w2 * iv;
                    if ((b0 >= 0.f) & (b1 >= 0.f) & (b2 >= 0.f)) {
                        pass = true; g0 = b0; g1 = b1; g2 = b2;
                        i0 = __float_as_int(r3.y); i1 = __float_as_int(r3.z); i2 = __float_as_int(r3.w);
                    }
                }
            }
            const unsigned long long hm = __ballot(pass);
            if (hm) {
                if (lane == (int)__builtin_ctzll(hm)) {   // lowest index = ref argmax
                    const int o = pid * 3;
                    out[o + 0] = g0 * attr[3 * i0 + 0] + g1 * attr[3 * i1 + 0] + g2 * attr[3 * i2 + 0];
                    out[o + 1] = g0 * attr[3 * i0 + 1] + g1 * attr[3 * i1 + 1] + g2 * attr[3 * i2 + 1];
                    out[o + 2] = g0 * attr[3 * i0 + 2] + g1 * attr[3 * i1 + 2] + g2 * attr[3 * i2 + 2];
                }
                found = true;
            }
        }
        if (!found && lane == 0) {
            const int o = pid * 3;
            out[o + 0] = 0.f; out[o + 1] = 0.f; out[o + 2] = 0.f;
        }
    }
}

// ---- fallback (tiny workspace / huge nTri): proven-correct wave-per-pixel scan ----
__global__ __launch_bounds__(256) void bake_wave(
    const float* __restrict__ uv, const int* __restrict__ faces,
    const float* __restrict__ attr, float* __restrict__ out,
    int res, int nTri)
{
    const int lane = threadIdx.x & 63;
    const int wid  = blockIdx.x * (blockDim.x >> 6) + (threadIdx.x >> 6);
    const int npix = res * res;
    if (wid >= npix) return;
    const int pyi = wid / res, pxi = wid - pyi * res;
    const float rf = (float)res;
    const float px = ((float)pxi + 0.5f) / rf, py = ((float)pyi + 0.5f) / rf;
    for (int base = 0; base < nTri; base += 64) {
        const int t = base + lane;
        bool hit = false; float b0 = 0, b1 = 0, b2 = 0; int i0 = 0, i1 = 0, i2 = 0;
        if (t < nTri) {
            i0 = faces[3 * t]; i1 = faces[3 * t + 1]; i2 = faces[3 * t + 2];
            const float ax = uv[2 * i0], ay = uv[2 * i0 + 1];
            const float bx = uv[2 * i1], by = uv[2 * i1 + 1];
            const float cx = uv[2 * i2], cy = uv[2 * i2 + 1];
            const float area = (bx - ax) * (cy - ay) - (by - ay) * (cx - ax);
            if (fabsf(area) > 1e-9f) {
                const float inv = 1.0f / area;
                b0 = ((cx - bx) * (py - by) - (cy - by) * (px - bx)) * inv;
                b1 = ((ax - cx) * (py - cy) - (ay - cy) * (px - cx)) * inv;
                b2 = ((bx - ax) * (py - ay) - (by - ay) * (px - ax)) * inv;
                hit = (b0 >= 0.f) & (b1 >= 0.f) & (b2 >= 0.f);
            }
        }
        const unsigned long long m = __ballot(hit);
        if (m) {
            const int src = (int)__builtin_ctzll(m);
            b0 = __shfl(b0, src, 64); b1 = __shfl(b1, src, 64); b2 = __shfl(b2, src, 64);
            const int J0 = __shfl(i0, src, 64), J1 = __shfl(i1, src, 64), J2 = __shfl(i2, src, 64);
            if (lane == 0) {
                const int o = wid * 3;
                out[o + 0] = b0 * attr[3 * J0] + b1 * attr[3 * J1] + b2 * attr[3 * J2];
                out[o + 1] = b0 * attr[3 * J0 + 1] + b1 * attr[3 * J1 + 1] + b2 * attr[3 * J2 + 1];
                out[o + 2] = b0 * attr[3 * J0 + 2] + b1 * attr[3 * J1 + 2] + b2 * attr[3 * J2 + 2];
            }
            return;
        }
    }
    if (lane == 0) { const int o = wid * 3; out[o] = 0.f; out[o + 1] = 0.f; out[o + 2] = 0.f; }
}

extern "C" void kernel_launch(void* const* d_in, const int* in_sizes, int n_in,
                              void* d_out, int out_size, void* d_ws, size_t ws_size,
                              hipStream_t stream) {
    const float* attr  = (const float*)d_in[0];
    const float* uv    = (const float*)d_in[1];
    const int*   faces = (const int*)d_in[2];
    float*       out   = (float*)d_out;

    const int nTri = in_sizes[2] / 3;
    const int res  = (int)(sqrt((double)(out_size / 3)) + 0.5);
    const int npix = res * res;

    const int nCellX = (res + CELLPX - 1) / CELLPX;
    const int nCells = nCellX * nCellX;

    const size_t recsB  = (size_t)nTri * 64;
    const size_t cntB   = (size_t)nCells * sizeof(int);
    const size_t listB  = (size_t)nCells * LCAP * sizeof(unsigned short);
    const size_t qcB    = 64;
    const size_t queueB = (size_t)npix * sizeof(unsigned);
    const size_t need   = recsB + cntB + listB + qcB + queueB;   // ~2.6 MB

    if (nTri <= 65535 && ws_size >= need) {
        char* p = (char*)d_ws;
        float* recs = (float*)p;                    p += recsB;
        int* counts = (int*)p;                      p += cntB;
        unsigned short* lists = (unsigned short*)p; p += listB;
        int* qCount = (int*)p;                      p += qcB;
        unsigned* queue = (unsigned*)p;

        bin32f<<<nCells, 1024, 0, stream>>>(uv, faces, recs, lists, counts, qCount,
                                            res, nTri, nCellX, nCells);
        dim3 grid((res + TILE - 1) / TILE, (res + TILE - 1) / TILE);
        bake16<<<grid, 256, 0, stream>>>(recs, lists, counts, attr, out, queue, qCount,
                                         res, nTri, nCellX);
        rescue<<<4096, 256, 0, stream>>>(recs, lists, counts, attr, out, queue, qCount,
                                         res, nTri, nCellX);
    } else {
        bake_wave<<<(npix + 3) / 4, 256, 0, stream>>>(uv, faces, attr, out, res, nTri);
    }
}

// Round 19
// 49.351 us; speedup vs baseline: 1.9088x; 1.0033x over previous
//
#include <hip/hip_runtime.h>
#include <math.h>

#pragma clang fp contract(off)

#define TILE 16
#define CELLPX 32
#define LCAP 2048      // per-cell ordered list capacity (u16); overflow -> raw-order scan
#define MAXS 64        // stage-1 scan depth = one LDS batch

__device__ __forceinline__ bool edgeMayPass(
    float qx, float qy, float ex, float ey, float s,
    float rx0, float rx1, float ry0, float ry1)
{
    const float A = s * ex;
    const float B = -s * ey;
    const float fy = A * ((A >= 0.f ? ry1 : ry0) - qy);
    const float fx = B * ((B >= 0.f ? rx1 : rx0) - qx);
    return (fy + fx) >= -1e-5f;   // conservative margin >> fp eval error
}

__device__ __forceinline__ bool satKeepRaw(
    const float4 r0, const float4 r1, const float4 r2, const float sgn,
    float rx0, float rx1, float ry0, float ry1)
{
    if (sgn == 0.f) return false;
    const float xmn = fminf(r2.x, fminf(r0.x, r1.x));
    const float xmx = fmaxf(r2.x, fmaxf(r0.x, r1.x));
    const float ymn = fminf(r2.y, fminf(r0.y, r1.y));
    const float ymx = fmaxf(r2.y, fmaxf(r0.y, r1.y));
    if (!((xmn <= rx1) & (xmx >= rx0) & (ymn <= ry1) & (ymx >= ry0))) return false;
    return edgeMayPass(r0.x, r0.y, r0.z, r0.w, sgn, rx0, rx1, ry0, ry1)
        && edgeMayPass(r1.x, r1.y, r1.z, r1.w, sgn, rx0, rx1, ry0, ry1)
        && edgeMayPass(r2.x, r2.y, r2.z, r2.w, sgn, rx0, rx1, ry0, ry1);
}

// K1: one 1024-thread block per 32px cell. SAT computed ON THE FLY from
// uv/faces; each block also materializes its own recs slice (distributed prep).
// Single barrier per iteration via double-buffered waveCnt.
// rec (16 dwords): [0]=bx [1]=by [2]=cx-bx [3]=cy-by | [4]=cx [5]=cy [6]=ax-cx [7]=ay-cy
//                  [8]=ax [9]=ay [10]=bx-ax [11]=by-ay | [12]=inv(0 if invalid) [13..15]=i0,i1,i2
__global__ __launch_bounds__(1024) void bin32f(
    const float* __restrict__ uv, const int* __restrict__ faces,
    float* __restrict__ recs, unsigned short* __restrict__ lists,
    int* __restrict__ counts, int* __restrict__ qCount,
    int res, int nTri, int nCellX, int nCells)
{
    __shared__ int waveCnt[2][16];
    if (blockIdx.x == 0 && threadIdx.x == 0) *qCount = 0;   // re-zeroed every replay

    // ---- distributed recs materialization: this block's triangle slice ----
    const int segSz = (nTri + nCells - 1) / nCells;
    const int rBase = blockIdx.x * segSz;
    for (int t = rBase + threadIdx.x; t < min(nTri, rBase + segSz); t += 1024) {
        const int i0 = faces[3 * t], i1 = faces[3 * t + 1], i2 = faces[3 * t + 2];
        const float ax = uv[2 * i0], ay = uv[2 * i0 + 1];
        const float bx = uv[2 * i1], by = uv[2 * i1 + 1];
        const float cx = uv[2 * i2], cy = uv[2 * i2 + 1];
        const float area = (bx - ax) * (cy - ay) - (by - ay) * (cx - ax);  // exact ref op
        const bool valid = fabsf(area) > 1e-9f;
        float* r = recs + 16 * t;
        r[0] = bx; r[1] = by; r[2]  = cx - bx; r[3]  = cy - by;
        r[4] = cx; r[5] = cy; r[6]  = ax - cx; r[7]  = ay - cy;
        r[8] = ax; r[9] = ay; r[10] = bx - ax; r[11] = by - ay;
        r[12] = valid ? 1.0f / area : 0.f;    // IEEE div, matches reference
        ((int*)r)[13] = i0; ((int*)r)[14] = i1; ((int*)r)[15] = i2;
    }

    // ---- binning: index-order scan -> globally ordered candidate list ----
    const int cell = blockIdx.x;
    const int cellX = cell % nCellX, cellY = cell / nCellX;
    const float rf = (float)res;
    const float rx0 = ((float)(cellX * CELLPX) - 1.5f) / rf;
    const float rx1 = ((float)(cellX * CELLPX + CELLPX) + 1.5f) / rf;
    const float ry0 = ((float)(cellY * CELLPX) - 1.5f) / rf;
    const float ry1 = ((float)(cellY * CELLPX + CELLPX) + 1.5f) / rf;

    const int lane = threadIdx.x & 63, wv = threadIdx.x >> 6;
    unsigned short* myList = lists + (size_t)cell * LCAP;

    int cnt = 0, ph = 0;
    for (int base = 0; base < nTri; base += 1024) {
        const int t = base + threadIdx.x;
        bool keep = false;
        if (t < nTri) {
            const int i0 = faces[3 * t], i1 = faces[3 * t + 1], i2 = faces[3 * t + 2];
            const float ax = uv[2 * i0], ay = uv[2 * i0 + 1];
            const float bx = uv[2 * i1], by = uv[2 * i1 + 1];
            const float cx = uv[2 * i2], cy = uv[2 * i2 + 1];
            const float area = (bx - ax) * (cy - ay) - (by - ay) * (cx - ax);  // exact ref op
            const float sgn = (fabsf(area) > 1e-9f) ? ((area >= 0.f) ? 1.f : -1.f) : 0.f;
            const float4 r0 = make_float4(bx, by, cx - bx, cy - by);
            const float4 r1 = make_float4(cx, cy, ax - cx, ay - cy);
            const float4 r2 = make_float4(ax, ay, bx - ax, by - ay);
            keep = satKeepRaw(r0, r1, r2, sgn, rx0, rx1, ry0, ry1);
        }
        const unsigned long long m = __ballot(keep);
        if (lane == 0) waveCnt[ph][wv] = __popcll(m);
        __syncthreads();                       // one barrier/iter (phase dbuf is race-free)
        int off = 0, tot = 0;
        #pragma unroll
        for (int w = 0; w < 16; ++w) {
            if (w < wv) off += waveCnt[ph][w];
            tot += waveCnt[ph][w];
        }
        const int pre = __popcll(m & ((1ull << lane) - 1ull));
        if (keep) {
            const int slot = cnt + off + pre;
            if (slot < LCAP) myList[slot] = (unsigned short)t;
        }
        cnt += tot;   // > LCAP => raw-order mode (central cells: shallow hits anyway)
        ph ^= 1;
    }
    if (threadIdx.x == 0) counts[cell] = cnt;
}

// K2: one 16px tile per block, EXACTLY one 64-candidate LDS batch, scanned
// with a depth-1 ping-pong register pipeline. Unresolved pixels with deeper
// lists are pushed to a compact queue (wave-aggregated atomicAdd).
__global__ __launch_bounds__(256) void bake16(
    const float* __restrict__ recs, const unsigned short* __restrict__ lists,
    const int* __restrict__ counts, const float* __restrict__ attr,
    float* __restrict__ out, unsigned* __restrict__ queue, int* __restrict__ qCount,
    int res, int nTri, int nCellX)
{
    __shared__ float4 L0[MAXS], L1[MAXS], L2[MAXS], L3[MAXS];
    __shared__ unsigned long long smask[4];

    const int tx = threadIdx.x & 15, ty = threadIdx.x >> 4;
    const int pxi = blockIdx.x * TILE + tx;
    const int pyi = blockIdx.y * TILE + ty;
    const bool inb = (pxi < res) && (pyi < res);
    const float rf = (float)res;
    const float px = ((float)pxi + 0.5f) / rf;   // exact reference op
    const float py = ((float)pyi + 0.5f) / rf;

    const int cell = ((blockIdx.y * TILE) / CELLPX) * nCellX + (blockIdx.x * TILE) / CELLPX;
    const int count = counts[cell];              // uniform
    const bool useList = (count <= LCAP);
    const int total = useList ? count : nTri;
    const int n = min(MAXS, total);
    const unsigned short* myList = lists + (size_t)cell * LCAP;

    const int lane = threadIdx.x & 63, wv = threadIdx.x >> 6;

    // ---- fill one batch + sign-of-inv mask ----
    bool sb = false;
    if (threadIdx.x < n) {
        const int t = useList ? (int)myList[threadIdx.x] : threadIdx.x;
        const float4* R = (const float4*)(recs + 16 * t);
        float4 r0 = R[0];
        const float4 r1 = R[1], r2 = R[2], r3 = R[3];
        sb = (__float_as_uint(r3.x) >> 31) != 0;
        if (r3.x == 0.f)   // invalid tri (raw mode): poison edge0 -> never passes
            r0 = make_float4(0.f, __builtin_huge_valf(), 1.f, 0.f);
        L0[threadIdx.x] = r0; L1[threadIdx.x] = r1;
        L2[threadIdx.x] = r2; L3[threadIdx.x] = r3;
    }
    const unsigned long long bal = __ballot(sb);
    if (lane == 0) smask[wv] = bal;
    __syncthreads();
    const unsigned long long m0 = smask[0], m1 = smask[1];

    // pass test: b>=0  <=>  w==0 or signbit(w)==signbit(inv)
    auto passf = [&](const float4 T0, const float4 T1, const float4 T2,
                     unsigned sv) -> unsigned {
        const float w0 = T0.z * (py - T0.y) - T0.w * (px - T0.x);
        const float w1 = T1.z * (py - T1.y) - T1.w * (px - T1.x);
        const float w2 = T2.z * (py - T2.y) - T2.w * (px - T2.x);
        const bool c0 = (w0 == 0.f) | ((__float_as_uint(w0) >> 31) == sv);
        const bool c1 = (w1 == 0.f) | ((__float_as_uint(w1) >> 31) == sv);
        const bool c2 = (w2 == 0.f) | ((__float_as_uint(w2) >> 31) == sv);
        return (unsigned)(c0 & c1 & c2);
    };

    bool hit = false;
    int kWin = 0;

    if (inb && n > 0) {
        const int last = n - 1;
        float4 pA0, pA1, pA2, pB0, pB1, pB2, pC0, pC1, pC2, pD0, pD1, pD2;
        float4 qA0, qA1, qA2, qB0, qB1, qB2, qC0, qC1, qC2, qD0, qD1, qD2;

        #define LOADSET(V, BASE)                                                 \
            { const int _ka = min((BASE), last),     _kb = min((BASE) + 1, last),\
                        _kc = min((BASE) + 2, last), _kd = min((BASE) + 3, last);\
              V##A0 = L0[_ka]; V##A1 = L1[_ka]; V##A2 = L2[_ka];                 \
              V##B0 = L0[_kb]; V##B1 = L1[_kb]; V##B2 = L2[_kb];                 \
              V##C0 = L0[_kc]; V##C1 = L1[_kc]; V##C2 = L2[_kc];                 \
              V##D0 = L0[_kd]; V##D1 = L1[_kd]; V##D2 = L2[_kd]; }

        #define TESTSET(V, BASE)                                                 \
            if (!hit) {                                                          \
                const int _ka = min((BASE), last),     _kb = min((BASE) + 1, last),\
                          _kc = min((BASE) + 2, last), _kd = min((BASE) + 3, last);\
                const unsigned long long mw = ((BASE) & 64) ? m1 : m0;           \
                unsigned pm = 0u;                                                \
                pm |= passf(V##A0, V##A1, V##A2,                                 \
                            (unsigned)((mw >> (_ka & 63)) & 1ull)) << 0;         \
                pm |= passf(V##B0, V##B1, V##B2,                                 \
                            (unsigned)((mw >> (_kb & 63)) & 1ull)) << 1;         \
                pm |= passf(V##C0, V##C1, V##C2,                                 \
                            (unsigned)((mw >> (_kc & 63)) & 1ull)) << 2;         \
                pm |= passf(V##D0, V##D1, V##D2,                                 \
                            (unsigned)((mw >> (_kd & 63)) & 1ull)) << 3;         \
                if (pm) { hit = true;                                            \
                          kWin = min((BASE) + (int)__builtin_ctz(pm), last); }   \
            }

        LOADSET(p, 0)
        for (int i = 0; i < n && !hit; i += 8) {
            LOADSET(q, i + 4)
            __builtin_amdgcn_sched_barrier(0);   // loads issued BEFORE p-tests
            TESTSET(p, i)
            LOADSET(p, i + 8)
            __builtin_amdgcn_sched_barrier(0);   // loads issued BEFORE q-tests
            TESTSET(q, i + 4)
        }
        #undef LOADSET
        #undef TESTSET
    }

    if (inb && hit) {   // recompute exact reference barycentrics for the winner
        const int o = (pyi * res + pxi) * 3;
        const float4 E0 = L0[kWin], E1 = L1[kWin], E2 = L2[kWin], E3 = L3[kWin];
        const float w0 = E0.z * (py - E0.y) - E0.w * (px - E0.x);
        const float w1 = E1.z * (py - E1.y) - E1.w * (px - E1.x);
        const float w2 = E2.z * (py - E2.y) - E2.w * (px - E2.x);
        const float iv = E3.x;
        const float g0 = w0 * iv, g1 = w1 * iv, g2 = w2 * iv;
        const int j0 = __float_as_int(E3.y), j1 = __float_as_int(E3.z), j2 = __float_as_int(E3.w);
        out[o + 0] = g0 * attr[3 * j0 + 0] + g1 * attr[3 * j1 + 0] + g2 * attr[3 * j2 + 0];
        out[o + 1] = g0 * attr[3 * j0 + 1] + g1 * attr[3 * j1 + 1] + g2 * attr[3 * j2 + 1];
        out[o + 2] = g0 * attr[3 * j0 + 2] + g1 * attr[3 * j1 + 2] + g2 * attr[3 * j2 + 2];
    } else if (inb && total <= MAXS) {   // complete list scanned: truly empty pixel
        const int o = (pyi * res + pxi) * 3;
        out[o + 0] = 0.f; out[o + 1] = 0.f; out[o + 2] = 0.f;
    }

    // ---- defer unresolved pixels: wave-aggregated queue push ----
    // (queue ORDER is nondeterministic; per-pixel processing & output are not)
    const bool defer = inb && !hit && (total > MAXS);
    const unsigned long long dm = __ballot(defer);
    if (dm) {
        const int leader = (int)__builtin_ctzll(dm);
        int base = 0;
        if (lane == leader) base = atomicAdd(qCount, __popcll(dm));
        base = __shfl(base, leader, 64);
        if (defer) {
            const int pre = __popcll(dm & ((1ull << lane) - 1ull));
            queue[base + pre] = (unsigned)(pyi * res + pxi);
        }
    }
}

// K3: one wave per queued straggler (grid-stride), with a depth-1 software
// pipeline over 64-candidate groups (next group's list+recs loads issued
// before testing the current group -> gather latency hidden).
__global__ __launch_bounds__(256) void rescue(
    const float* __restrict__ recs, const unsigned short* __restrict__ lists,
    const int* __restrict__ counts, const float* __restrict__ attr,
    float* __restrict__ out, const unsigned* __restrict__ queue,
    const int* __restrict__ qCount, int res, int nTri, int nCellX)
{
    const int lane = threadIdx.x & 63;
    const int wid  = blockIdx.x * 4 + (threadIdx.x >> 6);
    const int nW   = gridDim.x * 4;
    const float rf = (float)res;
    const int qn = *qCount;   // uniform

    for (int k = wid; k < qn; k += nW) {
        const int pid = (int)queue[k];
        const int pyi = pid / res, pxi = pid - pyi * res;
        const float px = ((float)pxi + 0.5f) / rf;
        const float py = ((float)pyi + 0.5f) / rf;
        const int cell = (pyi / CELLPX) * nCellX + pxi / CELLPX;
        const int count = counts[cell];
        const bool useList = (count <= LCAP);
        const int total = useList ? count : nTri;
        const unsigned short* myList = lists + (size_t)cell * LCAP;

        bool found = false;
        if (total > MAXS) {
            const int lastI = total - 1;
            float4 c0, c1, c2, c3;
            {   // preload group 0
                const int ci = min(MAXS + lane, lastI);
                const int t = useList ? (int)myList[ci] : ci;
                const float4* R = (const float4*)(recs + 16 * t);
                c0 = R[0]; c1 = R[1]; c2 = R[2]; c3 = R[3];
            }
            for (int base = MAXS; base < total && !found; base += 64) {
                // ---- prefetch next group (latency hidden under current test) ----
                float4 n0 = make_float4(0.f, 0.f, 0.f, 0.f), n1 = n0, n2 = n0, n3 = n0;
                const int nbase = base + 64;
                if (nbase < total) {
                    const int ni = min(nbase + lane, lastI);
                    const int t = useList ? (int)myList[ni] : ni;
                    const float4* R = (const float4*)(recs + 16 * t);
                    n0 = R[0]; n1 = R[1]; n2 = R[2]; n3 = R[3];
                }
                __builtin_amdgcn_sched_barrier(0);   // loads issued BEFORE tests

                // ---- test current group ----
                const int idx = base + lane;
                bool pass = false;
                float g0 = 0.f, g1 = 0.f, g2 = 0.f; int i0 = 0, i1 = 0, i2 = 0;
                if (idx < total) {
                    const float iv = c3.x;
                    if (iv != 0.f) {
                        const float w0 = c0.z * (py - c0.y) - c0.w * (px - c0.x);
                        const float w1 = c1.z * (py - c1.y) - c1.w * (px - c1.x);
                        const float w2 = c2.z * (py - c2.y) - c2.w * (px - c2.x);
                        const float b0 = w0 * iv, b1 = w1 * iv, b2 = w2 * iv;
                        if ((b0 >= 0.f) & (b1 >= 0.f) & (b2 >= 0.f)) {
                            pass = true; g0 = b0; g1 = b1; g2 = b2;
                            i0 = __float_as_int(c3.y); i1 = __float_as_int(c3.z); i2 = __float_as_int(c3.w);
                        }
                    }
                }
                const unsigned long long hm = __ballot(pass);
                if (hm) {
                    if (lane == (int)__builtin_ctzll(hm)) {   // lowest index = ref argmax
                        const int o = pid * 3;
                        out[o + 0] = g0 * attr[3 * i0 + 0] + g1 * attr[3 * i1 + 0] + g2 * attr[3 * i2 + 0];
                        out[o + 1] = g0 * attr[3 * i0 + 1] + g1 * attr[3 * i1 + 1] + g2 * attr[3 * i2 + 1];
                        out[o + 2] = g0 * attr[3 * i0 + 2] + g1 * attr[3 * i1 + 2] + g2 * attr[3 * i2 + 2];
                    }
                    found = true;
                }
                c0 = n0; c1 = n1; c2 = n2; c3 = n3;
            }
        }
        if (!found && lane == 0) {
            const int o = pid * 3;
            out[o + 0] = 0.f; out[o + 1] = 0.f; out[o + 2] = 0.f;
        }
    }
}

// ---- fallback (tiny workspace / huge nTri): proven-correct wave-per-pixel scan ----
__global__ __launch_bounds__(256) void bake_wave(
    const float* __restrict__ uv, const int* __restrict__ faces,
    const float* __restrict__ attr, float* __restrict__ out,
    int res, int nTri)
{
    const int lane = threadIdx.x & 63;
    const int wid  = blockIdx.x * (blockDim.x >> 6) + (threadIdx.x >> 6);
    const int npix = res * res;
    if (wid >= npix) return;
    const int pyi = wid / res, pxi = wid - pyi * res;
    const float rf = (float)res;
    const float px = ((float)pxi + 0.5f) / rf, py = ((float)pyi + 0.5f) / rf;
    for (int base = 0; base < nTri; base += 64) {
        const int t = base + lane;
        bool hit = false; float b0 = 0, b1 = 0, b2 = 0; int i0 = 0, i1 = 0, i2 = 0;
        if (t < nTri) {
            i0 = faces[3 * t]; i1 = faces[3 * t + 1]; i2 = faces[3 * t + 2];
            const float ax = uv[2 * i0], ay = uv[2 * i0 + 1];
            const float bx = uv[2 * i1], by = uv[2 * i1 + 1];
            const float cx = uv[2 * i2], cy = uv[2 * i2 + 1];
            const float area = (bx - ax) * (cy - ay) - (by - ay) * (cx - ax);
            if (fabsf(area) > 1e-9f) {
                const float inv = 1.0f / area;
                b0 = ((cx - bx) * (py - by) - (cy - by) * (px - bx)) * inv;
                b1 = ((ax - cx) * (py - cy) - (ay - cy) * (px - cx)) * inv;
                b2 = ((bx - ax) * (py - ay) - (by - ay) * (px - ax)) * inv;
                hit = (b0 >= 0.f) & (b1 >= 0.f) & (b2 >= 0.f);
            }
        }
        const unsigned long long m = __ballot(hit);
        if (m) {
            const int src = (int)__builtin_ctzll(m);
            b0 = __shfl(b0, src, 64); b1 = __shfl(b1, src, 64); b2 = __shfl(b2, src, 64);
            const int J0 = __shfl(i0, src, 64), J1 = __shfl(i1, src, 64), J2 = __shfl(i2, src, 64);
            if (lane == 0) {
                const int o = wid * 3;
                out[o + 0] = b0 * attr[3 * J0] + b1 * attr[3 * J1] + b2 * attr[3 * J2];
                out[o + 1] = b0 * attr[3 * J0 + 1] + b1 * attr[3 * J1 + 1] + b2 * attr[3 * J2 + 1];
                out[o + 2] = b0 * attr[3 * J0 + 2] + b1 * attr[3 * J1 + 2] + b2 * attr[3 * J2 + 2];
            }
            return;
        }
    }
    if (lane == 0) { const int o = wid * 3; out[o] = 0.f; out[o + 1] = 0.f; out[o + 2] = 0.f; }
}

extern "C" void kernel_launch(void* const* d_in, const int* in_sizes, int n_in,
                              void* d_out, int out_size, void* d_ws, size_t ws_size,
                              hipStream_t stream) {
    const float* attr  = (const float*)d_in[0];
    const float* uv    = (const float*)d_in[1];
    const int*   faces = (const int*)d_in[2];
    float*       out   = (float*)d_out;

    const int nTri = in_sizes[2] / 3;
    const int res  = (int)(sqrt((double)(out_size / 3)) + 0.5);
    const int npix = res * res;

    const int nCellX = (res + CELLPX - 1) / CELLPX;
    const int nCells = nCellX * nCellX;

    const size_t recsB  = (size_t)nTri * 64;
    const size_t cntB   = (size_t)nCells * sizeof(int);
    const size_t listB  = (size_t)nCells * LCAP * sizeof(unsigned short);
    const size_t qcB    = 64;
    const size_t queueB = (size_t)npix * sizeof(unsigned);
    const size_t need   = recsB + cntB + listB + qcB + queueB;   // ~2.6 MB

    if (nTri <= 65535 && ws_size >= need) {
        char* p = (char*)d_ws;
        float* recs = (float*)p;                    p += recsB;
        int* counts = (int*)p;                      p += cntB;
        unsigned short* lists = (unsigned short*)p; p += listB;
        int* qCount = (int*)p;                      p += qcB;
        unsigned* queue = (unsigned*)p;

        bin32f<<<nCells, 1024, 0, stream>>>(uv, faces, recs, lists, counts, qCount,
                                            res, nTri, nCellX, nCells);
        dim3 grid((res + TILE - 1) / TILE, (res + TILE - 1) / TILE);
        bake16<<<grid, 256, 0, stream>>>(recs, lists, counts, attr, out, queue, qCount,
                                         res, nTri, nCellX);
        rescue<<<4096, 256, 0, stream>>>(recs, lists, counts, attr, out, queue, qCount,
                                         res, nTri, nCellX);
    } else {
        bake_wave<<<(npix + 3) / 4, 256, 0, stream>>>(uv, faces, attr, out, res, nTri);
    }
}